// Round 7
// baseline (46.508 us; speedup 1.0000x reference)
//
#include <hip/hip_runtime.h>

#define Bc 2048
#define Tc 50
#define Lc 30
#define Nc 1000
#define NFc 2
#define EMBc 32
#define SEMBc 12

typedef float f4 __attribute__((ext_vector_type(4)));
typedef int   i4 __attribute__((ext_vector_type(4)));

__global__ __launch_bounds__(256) void gnnsage_kernel(
    const int*   __restrict__ stops,      // B,T
    const float* __restrict__ x,          // B,L,N
    const float* __restrict__ x_dist,     // N
    const float* __restrict__ x_features, // B,NF
    const int*   __restrict__ x_week,     // B
    const int*   __restrict__ x_mask,     // B,N
    const float* __restrict__ emb_week,   // NWD,EMB
    const float* __restrict__ emb_stop,   // N,SEMB
    const float* __restrict__ W_l,        // L
    const float* __restrict__ b_l,        // 1
    const float* __restrict__ W_r,        // L
    const float* __restrict__ fc2_W,      // 48
    const float* __restrict__ fc2_b,      // 1
    float*       __restrict__ out)        // B,N
{
    __shared__ float wl[Nc];       // dot(x[b,:,n], W_l)  (for edge gather)
    __shared__ float seg_sum[Nc];
    __shared__ float seg_cnt[Nc];
    __shared__ int   s_st[Tc];
    __shared__ float s_cbp[2];
    __shared__ float s_redM[4];
    __shared__ float s_redS[4];

    const int b   = blockIdx.x;
    const int tid = threadIdx.x;
    const int wv  = tid >> 6;
    const int ln  = tid & 63;
    const float* xb = x + (size_t)b * (Lc * Nc);

    // ---- init (no barrier needed until B) ----
    if (tid < Nc / 4) {
        ((f4*)seg_sum)[tid] = (f4)0.f;
        ((f4*)seg_cnt)[tid] = (f4)0.f;
    }

    // ---- early independent loads ----
    i4 mk = (i4)0;
    f4 d4 = (f4)0.f;
    if (tid < Nc / 4) {
        mk = __builtin_nontemporal_load(((const i4*)(x_mask + (size_t)b * Nc)) + tid);
        d4 = ((const f4*)x_dist)[tid];
    }
    int st_t = 0;
    if (tid < Tc) { st_t = stops[b * Tc + tid]; s_st[tid] = st_t; }

    // ---- phase 1: single streaming pass over x[b] (nontemporal float4) ----
    f4 sr = (f4)0.f;   // x . W_r for this thread's 4 columns (stays in regs)
    if (tid < Nc / 4) {
        f4 sl = (f4)0.f;
        #pragma unroll
        for (int l = 0; l < Lc; ++l) {
            f4 v = __builtin_nontemporal_load((const f4*)(xb + l * Nc) + tid);
            sl += v * W_l[l];
            sr += v * W_r[l];
        }
        *((f4*)&wl[tid * 4]) = sl;
    }

    // ---- C_b partials (latency hidden under streaming of other waves/blocks) ----
    if (tid < 64) {
        // wave 0: per-stop embedding contribution
        float p = 0.f;
        if (tid < Tc) {
            const float* es = emb_stop + st_t * SEMBc;
            #pragma unroll
            for (int i = 0; i < SEMBc; ++i) p += es[i] * fc2_W[EMBc + NFc + i];
        }
        #pragma unroll
        for (int off = 32; off > 0; off >>= 1) p += __shfl_xor(p, off);
        if (tid == 0) s_cbp[0] = p;
    } else if (tid < 96) {
        // wave 1 lanes 0..31: week embedding dot + features + bias
        const int i = tid - 64;
        const int wk = x_week[b];
        float q = emb_week[wk * EMBc + i] * fc2_W[i];
        #pragma unroll
        for (int off = 16; off > 0; off >>= 1) q += __shfl_xor(q, off);
        if (tid == 64) {
            q += fc2_b[0];
            q += x_features[b * NFc + 0] * fc2_W[EMBc + 0];
            q += x_features[b * NFc + 1] * fc2_W[EMBc + 1];
            s_cbp[1] = q;
        }
    }
    __syncthreads();   // B: wl + seg-init + s_st + s_cbp ready

    // ---- phase 2: edge scatter spread over 4 waves (mean aggr, commuted) ----
    if (ln < 13) {
        const int e = ln * 4 + wv;       // 0..51
        if (e < Tc - 1) {
            int s = s_st[e], d = s_st[e + 1];
            atomicAdd(&seg_sum[d], wl[s]);
            atomicAdd(&seg_cnt[d], 1.0f);
        }
    }
    __syncthreads();   // C: seg arrays final

    // ---- phase 3: finalize logits (registers, vectorized) ----
    const float cb  = s_cbp[0] + s_cbp[1];
    const float w46 = fc2_W[EMBc + NFc + SEMBc];
    const float w47 = fc2_W[EMBc + NFc + SEMBc + 1];
    const float bl  = b_l[0];
    float lmax = -3.0e38f;
    f4 v4 = (f4)0.f;
    if (tid < Nc / 4) {
        const int n0 = tid * 4;
        f4 ss = *((const f4*)&seg_sum[n0]);
        f4 sc = *((const f4*)&seg_cnt[n0]);
        f4 a;
        a.x = sc.x > 0.f ? ss.x / sc.x : 0.f;
        a.y = sc.y > 0.f ? ss.y / sc.y : 0.f;
        a.z = sc.z > 0.f ? ss.z / sc.z : 0.f;
        a.w = sc.w > 0.f ? ss.w / sc.w : 0.f;
        v4 = cb + w46 * (a + bl + sr) + w47 * d4;
        lmax = fmaxf(fmaxf(v4.x, v4.y), fmaxf(v4.z, v4.w));
    }

    // ---- phase 4: fused online LSE (one cross-wave barrier) ----
    #pragma unroll
    for (int off = 32; off > 0; off >>= 1) lmax = fmaxf(lmax, __shfl_xor(lmax, off));
    float lsum = 0.f;
    if (tid < Nc / 4)
        lsum = __expf(v4.x - lmax) + __expf(v4.y - lmax) +
               __expf(v4.z - lmax) + __expf(v4.w - lmax);
    #pragma unroll
    for (int off = 32; off > 0; off >>= 1) lsum += __shfl_xor(lsum, off);
    if (ln == 0) { s_redM[wv] = lmax; s_redS[wv] = lsum; }
    __syncthreads();   // M: (m,s) pairs published
    const float m0 = s_redM[0], m1 = s_redM[1], m2 = s_redM[2], m3 = s_redM[3];
    const float mx = fmaxf(fmaxf(m0, m1), fmaxf(m2, m3));
    const float S  = s_redS[0] * __expf(m0 - mx) + s_redS[1] * __expf(m1 - mx)
                   + s_redS[2] * __expf(m2 - mx) + s_redS[3] * __expf(m3 - mx);
    const float lse = mx + __logf(S);

    // ---- phase 5: masked write (registers, nontemporal float4) ----
    if (tid < Nc / 4) {
        f4 o;
        o.x = mk.x ? -100000000.0f : (v4.x - lse);
        o.y = mk.y ? -100000000.0f : (v4.y - lse);
        o.z = mk.z ? -100000000.0f : (v4.z - lse);
        o.w = mk.w ? -100000000.0f : (v4.w - lse);
        __builtin_nontemporal_store(o, (f4*)(out + (size_t)b * Nc) + tid);
    }
}

extern "C" void kernel_launch(void* const* d_in, const int* in_sizes, int n_in,
                              void* d_out, int out_size, void* d_ws, size_t ws_size,
                              hipStream_t stream) {
    const int*   stops      = (const int*)  d_in[0];
    const float* x          = (const float*)d_in[1];
    const float* x_dist     = (const float*)d_in[2];
    const float* x_features = (const float*)d_in[3];
    const int*   x_week     = (const int*)  d_in[4];
    const int*   x_mask     = (const int*)  d_in[5];
    const float* emb_week   = (const float*)d_in[6];
    const float* emb_stop   = (const float*)d_in[7];
    const float* W_l        = (const float*)d_in[8];
    const float* b_l        = (const float*)d_in[9];
    const float* W_r        = (const float*)d_in[10];
    const float* fc2_W      = (const float*)d_in[11];
    const float* fc2_b      = (const float*)d_in[12];
    float* out = (float*)d_out;

    gnnsage_kernel<<<Bc, 256, 0, stream>>>(stops, x, x_dist, x_features, x_week,
                                           x_mask, emb_week, emb_stop, W_l, b_l,
                                           W_r, fc2_W, fc2_b, out);
}

// Round 8
// 44.192 us; speedup vs baseline: 1.0524x; 1.0524x over previous
//
#include <hip/hip_runtime.h>

#define Bc 2048
#define Tc 50
#define Lc 30
#define Nc 1000
#define NFc 2
#define EMBc 32
#define SEMBc 12

typedef float f4 __attribute__((ext_vector_type(4)));
typedef int   i4 __attribute__((ext_vector_type(4)));

__global__ __launch_bounds__(256) void gnnsage_kernel(
    const int*   __restrict__ stops,      // B,T
    const float* __restrict__ x,          // B,L,N
    const float* __restrict__ x_dist,     // N
    const float* __restrict__ x_features, // B,NF
    const int*   __restrict__ x_week,     // B
    const int*   __restrict__ x_mask,     // B,N
    const float* __restrict__ emb_week,   // NWD,EMB
    const float* __restrict__ emb_stop,   // N,SEMB
    const float* __restrict__ W_l,        // L
    const float* __restrict__ b_l,        // 1
    const float* __restrict__ W_r,        // L
    const float* __restrict__ fc2_W,      // 48
    const float* __restrict__ fc2_b,      // 1
    float*       __restrict__ out)        // B,N
{
    __shared__ float wl[Nc];       // dot(x[b,:,n], W_l)  (for edge gather)
    __shared__ float seg_sum[Nc];
    __shared__ float seg_cnt[Nc];
    __shared__ int   s_st[Tc];
    __shared__ float s_cbp[2];
    __shared__ float s_redM[4];
    __shared__ float s_redS[4];

    const int b   = blockIdx.x;
    const int tid = threadIdx.x;
    const int wv  = tid >> 6;
    const int ln  = tid & 63;
    const float* xb = x + (size_t)b * (Lc * Nc);

    // ---- init (no barrier needed until B) ----
    if (tid < Nc / 4) {
        ((f4*)seg_sum)[tid] = (f4)0.f;
        ((f4*)seg_cnt)[tid] = (f4)0.f;
    }

    // ---- early independent loads ----
    i4 mk = (i4)0;
    f4 d4 = (f4)0.f;
    if (tid < Nc / 4) {
        // keep NT: single-use per replay, stay OUT of L3 to leave room for x
        mk = __builtin_nontemporal_load(((const i4*)(x_mask + (size_t)b * Nc)) + tid);
        d4 = ((const f4*)x_dist)[tid];
    }
    int st_t = 0;
    if (tid < Tc) { st_t = stops[b * Tc + tid]; s_st[tid] = st_t; }

    // ---- phase 1: single streaming pass over x[b] ----
    // PLAIN loads (no NT): x is 245.8 MB < 256 MB L3 — let it stay resident
    // across graph replays so steady-state reads are L3 hits, not HBM.
    f4 sr = (f4)0.f;   // x . W_r for this thread's 4 columns (stays in regs)
    if (tid < Nc / 4) {
        f4 sl = (f4)0.f;
        #pragma unroll
        for (int l = 0; l < Lc; ++l) {
            f4 v = *((const f4*)(xb + l * Nc) + tid);
            sl += v * W_l[l];
            sr += v * W_r[l];
        }
        *((f4*)&wl[tid * 4]) = sl;
    }

    // ---- C_b partials (latency hidden under streaming of other waves/blocks) ----
    if (tid < 64) {
        // wave 0: per-stop embedding contribution
        float p = 0.f;
        if (tid < Tc) {
            const float* es = emb_stop + st_t * SEMBc;
            #pragma unroll
            for (int i = 0; i < SEMBc; ++i) p += es[i] * fc2_W[EMBc + NFc + i];
        }
        #pragma unroll
        for (int off = 32; off > 0; off >>= 1) p += __shfl_xor(p, off);
        if (tid == 0) s_cbp[0] = p;
    } else if (tid < 96) {
        // wave 1 lanes 0..31: week embedding dot + features + bias
        const int i = tid - 64;
        const int wk = x_week[b];
        float q = emb_week[wk * EMBc + i] * fc2_W[i];
        #pragma unroll
        for (int off = 16; off > 0; off >>= 1) q += __shfl_xor(q, off);
        if (tid == 64) {
            q += fc2_b[0];
            q += x_features[b * NFc + 0] * fc2_W[EMBc + 0];
            q += x_features[b * NFc + 1] * fc2_W[EMBc + 1];
            s_cbp[1] = q;
        }
    }
    __syncthreads();   // B: wl + seg-init + s_st + s_cbp ready

    // ---- phase 2: edge scatter spread over 4 waves (mean aggr, commuted) ----
    if (ln < 13) {
        const int e = ln * 4 + wv;       // 0..51
        if (e < Tc - 1) {
            int s = s_st[e], d = s_st[e + 1];
            atomicAdd(&seg_sum[d], wl[s]);
            atomicAdd(&seg_cnt[d], 1.0f);
        }
    }
    __syncthreads();   // C: seg arrays final

    // ---- phase 3: finalize logits (registers, vectorized) ----
    const float cb  = s_cbp[0] + s_cbp[1];
    const float w46 = fc2_W[EMBc + NFc + SEMBc];
    const float w47 = fc2_W[EMBc + NFc + SEMBc + 1];
    const float bl  = b_l[0];
    float lmax = -3.0e38f;
    f4 v4 = (f4)0.f;
    if (tid < Nc / 4) {
        const int n0 = tid * 4;
        f4 ss = *((const f4*)&seg_sum[n0]);
        f4 sc = *((const f4*)&seg_cnt[n0]);
        f4 a;
        a.x = sc.x > 0.f ? ss.x / sc.x : 0.f;
        a.y = sc.y > 0.f ? ss.y / sc.y : 0.f;
        a.z = sc.z > 0.f ? ss.z / sc.z : 0.f;
        a.w = sc.w > 0.f ? ss.w / sc.w : 0.f;
        v4 = cb + w46 * (a + bl + sr) + w47 * d4;
        lmax = fmaxf(fmaxf(v4.x, v4.y), fmaxf(v4.z, v4.w));
    }

    // ---- phase 4: fused online LSE (one cross-wave barrier) ----
    #pragma unroll
    for (int off = 32; off > 0; off >>= 1) lmax = fmaxf(lmax, __shfl_xor(lmax, off));
    float lsum = 0.f;
    if (tid < Nc / 4)
        lsum = __expf(v4.x - lmax) + __expf(v4.y - lmax) +
               __expf(v4.z - lmax) + __expf(v4.w - lmax);
    #pragma unroll
    for (int off = 32; off > 0; off >>= 1) lsum += __shfl_xor(lsum, off);
    if (ln == 0) { s_redM[wv] = lmax; s_redS[wv] = lsum; }
    __syncthreads();   // M: (m,s) pairs published
    const float m0 = s_redM[0], m1 = s_redM[1], m2 = s_redM[2], m3 = s_redM[3];
    const float mx = fmaxf(fmaxf(m0, m1), fmaxf(m2, m3));
    const float S  = s_redS[0] * __expf(m0 - mx) + s_redS[1] * __expf(m1 - mx)
                   + s_redS[2] * __expf(m2 - mx) + s_redS[3] * __expf(m3 - mx);
    const float lse = mx + __logf(S);

    // ---- phase 5: masked write (registers, nontemporal float4) ----
    if (tid < Nc / 4) {
        f4 o;
        o.x = mk.x ? -100000000.0f : (v4.x - lse);
        o.y = mk.y ? -100000000.0f : (v4.y - lse);
        o.z = mk.z ? -100000000.0f : (v4.z - lse);
        o.w = mk.w ? -100000000.0f : (v4.w - lse);
        __builtin_nontemporal_store(o, (f4*)(out + (size_t)b * Nc) + tid);
    }
}

extern "C" void kernel_launch(void* const* d_in, const int* in_sizes, int n_in,
                              void* d_out, int out_size, void* d_ws, size_t ws_size,
                              hipStream_t stream) {
    const int*   stops      = (const int*)  d_in[0];
    const float* x          = (const float*)d_in[1];
    const float* x_dist     = (const float*)d_in[2];
    const float* x_features = (const float*)d_in[3];
    const int*   x_week     = (const int*)  d_in[4];
    const int*   x_mask     = (const int*)  d_in[5];
    const float* emb_week   = (const float*)d_in[6];
    const float* emb_stop   = (const float*)d_in[7];
    const float* W_l        = (const float*)d_in[8];
    const float* b_l        = (const float*)d_in[9];
    const float* W_r        = (const float*)d_in[10];
    const float* fc2_W      = (const float*)d_in[11];
    const float* fc2_b      = (const float*)d_in[12];
    float* out = (float*)d_out;

    gnnsage_kernel<<<Bc, 256, 0, stream>>>(stops, x, x_dist, x_features, x_week,
                                           x_mask, emb_week, emb_stop, W_l, b_l,
                                           W_r, fc2_W, fc2_b, out);
}